// Round 7
// baseline (674.586 us; speedup 1.0000x reference)
//
#include <hip/hip_runtime.h>
#include <math.h>

#define NBROWS 262144

typedef float v2f __attribute__((ext_vector_type(2)));
__device__ __forceinline__ v2f pkset(float a, float b){ v2f r; r.x=a; r.y=b; return r; }
__device__ __forceinline__ v2f sp(float a){ return pkset(a,a); }

// ---- guaranteed packed fp32 math (VOP3P) ----
// d += a*b (per half)
__device__ __forceinline__ void fma2(v2f& d, v2f a, v2f b){
    asm("v_pk_fma_f32 %0, %1, %2, %0" : "+v"(d) : "v"(a), "v"(b));
}
// d -= a*b
__device__ __forceinline__ void fma2n(v2f& d, v2f a, v2f b){
    asm("v_pk_fma_f32 %0, %1, %2, %0 neg_lo:[1,0,0] neg_hi:[1,0,0]" : "+v"(d) : "v"(a), "v"(b));
}
// d.lo += a.lo*w.lo ; d.hi += a.hi*w.lo   (weight = w.lo broadcast)
__device__ __forceinline__ void fma2_lo(v2f& d, v2f a, v2f w){
    asm("v_pk_fma_f32 %0, %1, %2, %0 op_sel_hi:[1,0,1]" : "+v"(d) : "v"(a), "v"(w));
}
// d.lo += a.lo*w.hi ; d.hi += a.hi*w.hi   (weight = w.hi broadcast)
__device__ __forceinline__ void fma2_hi(v2f& d, v2f a, v2f w){
    asm("v_pk_fma_f32 %0, %1, %2, %0 op_sel:[0,1,0] op_sel_hi:[1,1,1]" : "+v"(d) : "v"(a), "v"(w));
}
__device__ __forceinline__ v2f mul2(v2f a, v2f b){
    v2f d; asm("v_pk_mul_f32 %0, %1, %2" : "=v"(d) : "v"(a), "v"(b)); return d;
}
__device__ __forceinline__ v2f sqrt2(v2f a){ return pkset(sqrtf(a.x), sqrtf(a.y)); }
__device__ __forceinline__ v2f rcp2(v2f a){ return pkset(1.f/a.x, 1.f/a.y); }

// ---------------- packed d_ws layout (floats) ----------------
// P1 [0,1152):     36 pairs (u<=v, u-major) x 32: [Sss w0..15][Svv0 w0..15]
// C1 [1152,2176):  (vv*8+u)*16 + w
// A1 [2176,2624):  28 pairs (u<v) x 16
// P2 [2624,4800):  136 pairs (u<=v) x 16: [Sss w0..7][Svv0 w0..7]
// C2 [4800,6848):  (vv*16+u)*8 + w
// A2 [6848,7808):  120 pairs (u<v) x 8
#define WS_TOT 7808

__device__ void pair_le(int p, int M, int& u, int& v) {
    u = 0; int cnt = M;
    while (p >= cnt) { p -= cnt; ++u; cnt = M - u; }
    v = u + p;
}
__device__ void pair_lt(int p, int M, int& u, int& v) {
    u = 0; int cnt = M - 1;
    while (p >= cnt) { p -= cnt; ++u; cnt = M - 1 - u; }
    v = u + 1 + p;
}

__global__ __launch_bounds__(256) void prep_kernel(
    const float* __restrict__ w1_ss, const float* __restrict__ w1_vv0,
    const float* __restrict__ w1_sv, const float* __restrict__ w1_vs,
    const float* __restrict__ w1_vv1,
    const float* __restrict__ w2_ss, const float* __restrict__ w2_vv0,
    const float* __restrict__ w2_sv, const float* __restrict__ w2_vs,
    const float* __restrict__ w2_vv1,
    float* __restrict__ ws)
{
    const float inv3 = 0.5773502691896258f;
    const float inv6 = 0.4082482904638631f;
    int i = blockIdx.x * 256 + threadIdx.x;
    if (i >= WS_TOT) return;
    float val = 0.f;
    if (i < 1152) {                       // P1
        int p = i >> 5, r = i & 31;
        int which = r >> 4, w = r & 15;
        int u, v; pair_le(p, 8, u, v);
        const float c0 = 0.08838834764831845f;
        const float* src = which ? w1_vv0 : w1_ss;
        float cc = which ? c0 * inv3 : c0;
        val = (u == v) ? cc * src[(u*8+v)*16+w]
                       : cc * (src[(u*8+v)*16+w] + src[(v*8+u)*16+w]);
    } else if (i < 2176) {                // C1
        int r = i - 1152; int vv = r >> 7, rem = r & 127, u = rem >> 4, w = rem & 15;
        val = (0.125f * inv3) * (w1_sv[(u*8+vv)*16+w] + w1_vs[(vv*8+u)*16+w]);
    } else if (i < 2624) {                // A1
        int r = i - 2176; int p = r >> 4, w = r & 15;
        int u, v; pair_lt(p, 8, u, v);
        val = (0.125f * inv6) * (w1_vv1[(u*8+v)*16+w] - w1_vv1[(v*8+u)*16+w]);
    } else if (i < 4800) {                // P2
        int r = i - 2624; int p = r >> 4, rr = r & 15, which = rr >> 3, w = rr & 7;
        int u, v; pair_le(p, 16, u, v);
        const float c0 = 0.04419417382415922f;
        const float* src = which ? w2_vv0 : w2_ss;
        float cc = which ? c0 * inv3 : c0;
        val = (u == v) ? cc * src[(u*16+v)*8+w]
                       : cc * (src[(u*16+v)*8+w] + src[(v*16+u)*8+w]);
    } else if (i < 6848) {                // C2
        int r = i - 4800; int vv = r >> 7, rem = r & 127, u = rem >> 3, w = rem & 7;
        val = (0.0625f * inv3) * (w2_sv[(u*16+vv)*8+w] + w2_vs[(vv*16+u)*8+w]);
    } else {                              // A2
        int r = i - 6848; int p = r >> 3, w = r & 7;
        int u, v; pair_lt(p, 16, u, v);
        val = (0.0625f * inv6) * (w2_vv1[(u*16+v)*8+w] - w2_vv1[(v*16+u)*8+w]);
    }
    ws[i] = val;
}

// ---------------- layer 1: 8 -> 16, chunk of 8 w ----------------
// v2f = (rowA, rowB). Weights read b64 (w,w+1) and broadcast per-half via op_sel.
template<int W0>
__device__ __forceinline__ void l1_chunk(const float* Wl,
    const v2f (&s)[8], const v2f (&vx1)[8], const v2f (&vy1)[8], const v2f (&vz1)[8],
    v2f (&ys)[16], v2f (&vx)[16], v2f (&vy)[16], v2f (&vz)[16])
{
#pragma unroll
    for (int w = 0; w < 8; ++w) { ys[W0+w]=sp(0.f); vx[W0+w]=sp(0.f); vy[W0+w]=sp(0.f); vz[W0+w]=sp(0.f); }
    {   // symmetric ss + vv0
        int p = 0;
#pragma unroll
        for (int u = 0; u < 8; ++u)
#pragma unroll
        for (int vv = u; vv < 8; ++vv) {
            v2f pp = mul2(s[u], s[vv]);
            v2f dd = mul2(vx1[u], vx1[vv]); fma2(dd, vy1[u], vy1[vv]); fma2(dd, vz1[u], vz1[vv]);
            const v2f* qa = reinterpret_cast<const v2f*>(Wl + p*32 + W0);
            const v2f* qb = reinterpret_cast<const v2f*>(Wl + p*32 + 16 + W0);
#pragma unroll
            for (int j = 0; j < 4; ++j) {
                v2f wa = qa[j], wb = qb[j];
                fma2_lo(ys[W0+2*j],   pp, wa); fma2_hi(ys[W0+2*j+1], pp, wa);
                fma2_lo(ys[W0+2*j],   dd, wb); fma2_hi(ys[W0+2*j+1], dd, wb);
            }
            ++p;
        }
    }
    // combined sv+vs
#pragma unroll
    for (int vv = 0; vv < 8; ++vv) {
        v2f tw[8];
#pragma unroll
        for (int w = 0; w < 8; ++w) tw[w] = sp(0.f);
#pragma unroll
        for (int u = 0; u < 8; ++u) {
            const v2f* qc = reinterpret_cast<const v2f*>(Wl + 1152 + (vv*8+u)*16 + W0);
#pragma unroll
            for (int j = 0; j < 4; ++j) {
                v2f wc = qc[j];
                fma2_lo(tw[2*j], s[u], wc); fma2_hi(tw[2*j+1], s[u], wc);
            }
        }
#pragma unroll
        for (int w = 0; w < 8; ++w) {
            fma2(vx[W0+w], tw[w], vx1[vv]);
            fma2(vy[W0+w], tw[w], vy1[vv]);
            fma2(vz[W0+w], tw[w], vz1[vv]);
        }
    }
    {   // antisymmetric cross
        int p = 0;
#pragma unroll
        for (int u = 0; u < 8; ++u)
#pragma unroll
        for (int vv = u + 1; vv < 8; ++vv) {
            v2f cx = mul2(vy1[u], vz1[vv]); fma2n(cx, vz1[u], vy1[vv]);
            v2f cy = mul2(vz1[u], vx1[vv]); fma2n(cy, vx1[u], vz1[vv]);
            v2f cz = mul2(vx1[u], vy1[vv]); fma2n(cz, vy1[u], vx1[vv]);
            const v2f* qa = reinterpret_cast<const v2f*>(Wl + 2176 + p*16 + W0);
#pragma unroll
            for (int j = 0; j < 4; ++j) {
                v2f wa = qa[j];
                fma2_lo(vx[W0+2*j], cx, wa); fma2_hi(vx[W0+2*j+1], cx, wa);
                fma2_lo(vy[W0+2*j], cy, wa); fma2_hi(vy[W0+2*j+1], cy, wa);
                fma2_lo(vz[W0+2*j], cz, wa); fma2_hi(vz[W0+2*j+1], cz, wa);
            }
            ++p;
        }
    }
}

// ---------------- layer 2: 16 -> 8, chunk of 4 w ----------------
template<int W0>
__device__ __forceinline__ void l2_chunk(const float* Wl,
    const v2f (&s)[16], const v2f (&vx1)[16], const v2f (&vy1)[16], const v2f (&vz1)[16],
    v2f (&zs)[8], v2f (&zx)[8], v2f (&zy)[8], v2f (&zz)[8])
{
#pragma unroll
    for (int w = 0; w < 4; ++w) { zs[W0+w]=sp(0.f); zx[W0+w]=sp(0.f); zy[W0+w]=sp(0.f); zz[W0+w]=sp(0.f); }
    {   // symmetric
        int p = 0;
#pragma unroll
        for (int u = 0; u < 16; ++u)
#pragma unroll
        for (int vv = u; vv < 16; ++vv) {
            v2f pp = mul2(s[u], s[vv]);
            v2f dd = mul2(vx1[u], vx1[vv]); fma2(dd, vy1[u], vy1[vv]); fma2(dd, vz1[u], vz1[vv]);
            const v2f* qa = reinterpret_cast<const v2f*>(Wl + 2624 + p*16 + W0);
            const v2f* qb = reinterpret_cast<const v2f*>(Wl + 2624 + p*16 + 8 + W0);
#pragma unroll
            for (int j = 0; j < 2; ++j) {
                v2f wa = qa[j], wb = qb[j];
                fma2_lo(zs[W0+2*j],   pp, wa); fma2_hi(zs[W0+2*j+1], pp, wa);
                fma2_lo(zs[W0+2*j],   dd, wb); fma2_hi(zs[W0+2*j+1], dd, wb);
            }
            ++p;
        }
    }
#pragma unroll
    for (int vv = 0; vv < 16; ++vv) {
        v2f tw[4];
#pragma unroll
        for (int w = 0; w < 4; ++w) tw[w] = sp(0.f);
#pragma unroll
        for (int u = 0; u < 16; ++u) {
            const v2f* qc = reinterpret_cast<const v2f*>(Wl + 4800 + (vv*16+u)*8 + W0);
#pragma unroll
            for (int j = 0; j < 2; ++j) {
                v2f wc = qc[j];
                fma2_lo(tw[2*j], s[u], wc); fma2_hi(tw[2*j+1], s[u], wc);
            }
        }
#pragma unroll
        for (int w = 0; w < 4; ++w) {
            fma2(zx[W0+w], tw[w], vx1[vv]);
            fma2(zy[W0+w], tw[w], vy1[vv]);
            fma2(zz[W0+w], tw[w], vz1[vv]);
        }
    }
    {   // cross
        int p = 0;
#pragma unroll
        for (int u = 0; u < 16; ++u)
#pragma unroll
        for (int vv = u + 1; vv < 16; ++vv) {
            v2f cx = mul2(vy1[u], vz1[vv]); fma2n(cx, vz1[u], vy1[vv]);
            v2f cy = mul2(vz1[u], vx1[vv]); fma2n(cy, vx1[u], vz1[vv]);
            v2f cz = mul2(vx1[u], vy1[vv]); fma2n(cz, vy1[u], vx1[vv]);
            const v2f* qa = reinterpret_cast<const v2f*>(Wl + 6848 + p*8 + W0);
#pragma unroll
            for (int j = 0; j < 2; ++j) {
                v2f wa = qa[j];
                fma2_lo(zx[W0+2*j], cx, wa); fma2_hi(zx[W0+2*j+1], cx, wa);
                fma2_lo(zy[W0+2*j], cy, wa); fma2_hi(zy[W0+2*j+1], cy, wa);
                fma2_lo(zz[W0+2*j], cz, wa); fma2_hi(zz[W0+2*j+1], cz, wa);
            }
            ++p;
        }
    }
}

// ---------------- norms: packed across the two rows (halves independent) ----
__device__ __forceinline__ void si_norm16_p(v2f (&ys)[16], v2f (&vx)[16], v2f (&vy)[16], v2f (&vz)[16])
{
    v2f a = sp(0.f);
#pragma unroll
    for (int j = 0; j < 16; ++j) a += ys[j];
    v2f m = a * sp(1.f/16);
    v2f var = sp(0.f);
#pragma unroll
    for (int j = 0; j < 16; ++j) { v2f d = ys[j] - m; fma2(var, d, d); }
    v2f inv = rcp2(sqrt2(var * sp(1.f/15)) + sp(1e-9f));
#pragma unroll
    for (int j = 0; j < 16; ++j) ys[j] = mul2(ys[j], inv);

    v2f n[16]; v2f sn = sp(0.f);
#pragma unroll
    for (int j = 0; j < 16; ++j) {
        v2f nn = mul2(vx[j], vx[j]); fma2(nn, vy[j], vy[j]); fma2(nn, vz[j], vz[j]);
        n[j] = sqrt2(nn + sp(1e-9f));
        sn += n[j];
    }
    v2f mn = sn * sp(1.f/16);
    v2f vr = sp(0.f);
#pragma unroll
    for (int j = 0; j < 16; ++j) { v2f d = n[j] - mn; fma2(vr, d, d); }
    v2f invv = rcp2(sqrt2(vr * sp(1.f/15)) + sp(1e-9f));
#pragma unroll
    for (int j = 0; j < 16; ++j) { vx[j]=mul2(vx[j],invv); vy[j]=mul2(vy[j],invv); vz[j]=mul2(vz[j],invv); }
}

__device__ __forceinline__ void tv_norm16_p(v2f (&ys)[16], v2f (&vx)[16], v2f (&vy)[16], v2f (&vz)[16])
{
    v2f ss = sp(0.f);
#pragma unroll
    for (int j = 0; j < 16; ++j) fma2(ss, ys[j], ys[j]);
    v2f inv = rcp2(sqrt2(ss + sp(1e-6f)));
#pragma unroll
    for (int j = 0; j < 16; ++j) ys[j] = mul2(ys[j], inv);

    v2f sx = sp(0.f), sy = sp(0.f), sz = sp(0.f);
#pragma unroll
    for (int j = 0; j < 16; ++j) { fma2(sx, vx[j], vx[j]); fma2(sy, vy[j], vy[j]); fma2(sz, vz[j], vz[j]); }
    v2f nm = (sqrt2(sx + sp(1e-6f)) + sqrt2(sy + sp(1e-6f)) + sqrt2(sz + sp(1e-6f))) * sp(1.f/3.f);
    v2f invv = rcp2(nm + sp(1e-6f));
#pragma unroll
    for (int j = 0; j < 16; ++j) { vx[j]=mul2(vx[j],invv); vy[j]=mul2(vy[j],invv); vz[j]=mul2(vz[j],invv); }
}

__device__ __forceinline__ void si_norm8_p(v2f (&zs)[8], v2f (&zx)[8], v2f (&zy)[8], v2f (&zz)[8])
{
    v2f a = sp(0.f);
#pragma unroll
    for (int j = 0; j < 8; ++j) a += zs[j];
    v2f m = a * sp(1.f/8);
    v2f var = sp(0.f);
#pragma unroll
    for (int j = 0; j < 8; ++j) { v2f d = zs[j] - m; fma2(var, d, d); }
    v2f inv = rcp2(sqrt2(var * sp(1.f/7)) + sp(1e-9f));
#pragma unroll
    for (int j = 0; j < 8; ++j) zs[j] = mul2(zs[j], inv);

    v2f n[8]; v2f sn = sp(0.f);
#pragma unroll
    for (int j = 0; j < 8; ++j) {
        v2f nn = mul2(zx[j], zx[j]); fma2(nn, zy[j], zy[j]); fma2(nn, zz[j], zz[j]);
        n[j] = sqrt2(nn + sp(1e-9f));
        sn += n[j];
    }
    v2f mn = sn * sp(1.f/8);
    v2f vr = sp(0.f);
#pragma unroll
    for (int j = 0; j < 8; ++j) { v2f d = n[j] - mn; fma2(vr, d, d); }
    v2f invv = rcp2(sqrt2(vr * sp(1.f/7)) + sp(1e-9f));
#pragma unroll
    for (int j = 0; j < 8; ++j) { zx[j]=mul2(zx[j],invv); zy[j]=mul2(zy[j],invv); zz[j]=mul2(zz[j],invv); }
}

__device__ __forceinline__ float fast_tanh(float x) {
    return 1.f - 2.f / (__expf(2.f * x) + 1.f);
}

// 2 rows/thread (v2f halves = rows base+t, base+t+256). __launch_bounds__(256)
// only (R2). b64-max weight reads (R5). Chunk+fence skeleton (R4/R6).
__global__ __launch_bounds__(256) void DoubleLayer_main_kernel(
    const float* __restrict__ x,
    const float* __restrict__ ws,
    float* __restrict__ out)
{
    __shared__ float Wl[WS_TOT];

    int t = threadIdx.x;
    int rA = blockIdx.x * 512 + t;
    int rB = rA + 256;
    const float4* xa = reinterpret_cast<const float4*>(x + (size_t)rA * 32);
    const float4* xb = reinterpret_cast<const float4*>(x + (size_t)rB * 32);
    float4 a0 = xa[0], a1 = xa[1], a2 = xa[2], a3 = xa[3];
    float4 a4 = xa[4], a5 = xa[5], a6 = xa[6], a7 = xa[7];
    float4 b0 = xb[0], b1 = xb[1], b2 = xb[2], b3 = xb[3];
    float4 b4 = xb[4], b5 = xb[5], b6 = xb[6], b7 = xb[7];

    // stage packed weights: 1952 float4
#pragma unroll
    for (int i = 0; i < 8; ++i) {
        int idx = t + i * 256;
        if (idx < WS_TOT/4)
            reinterpret_cast<float4*>(Wl)[idx] = reinterpret_cast<const float4*>(ws)[idx];
    }
    __syncthreads();

    v2f s1[8], v1x[8], v1y[8], v1z[8];
    s1[0] = pkset(fast_tanh(a0.x), fast_tanh(b0.x));
    s1[1] = pkset(fast_tanh(a0.y), fast_tanh(b0.y));
    s1[2] = pkset(fast_tanh(a0.z), fast_tanh(b0.z));
    s1[3] = pkset(fast_tanh(a0.w), fast_tanh(b0.w));
    s1[4] = pkset(fast_tanh(a1.x), fast_tanh(b1.x));
    s1[5] = pkset(fast_tanh(a1.y), fast_tanh(b1.y));
    s1[6] = pkset(fast_tanh(a1.z), fast_tanh(b1.z));
    s1[7] = pkset(fast_tanh(a1.w), fast_tanh(b1.w));
    v1x[0]=pkset(a2.x,b2.x); v1y[0]=pkset(a2.y,b2.y); v1z[0]=pkset(a2.z,b2.z);
    v1x[1]=pkset(a2.w,b2.w); v1y[1]=pkset(a3.x,b3.x); v1z[1]=pkset(a3.y,b3.y);
    v1x[2]=pkset(a3.z,b3.z); v1y[2]=pkset(a3.w,b3.w); v1z[2]=pkset(a4.x,b4.x);
    v1x[3]=pkset(a4.y,b4.y); v1y[3]=pkset(a4.z,b4.z); v1z[3]=pkset(a4.w,b4.w);
    v1x[4]=pkset(a5.x,b5.x); v1y[4]=pkset(a5.y,b5.y); v1z[4]=pkset(a5.z,b5.z);
    v1x[5]=pkset(a5.w,b5.w); v1y[5]=pkset(a6.x,b6.x); v1z[5]=pkset(a6.y,b6.y);
    v1x[6]=pkset(a6.z,b6.z); v1y[6]=pkset(a6.w,b6.w); v1z[6]=pkset(a7.x,b7.x);
    v1x[7]=pkset(a7.y,b7.y); v1y[7]=pkset(a7.z,b7.z); v1z[7]=pkset(a7.w,b7.w);

    v2f ys[16], vx[16], vy[16], vz[16];
    l1_chunk<0>(Wl, s1, v1x, v1y, v1z, ys, vx, vy, vz);
    __builtin_amdgcn_sched_barrier(0);
    l1_chunk<8>(Wl, s1, v1x, v1y, v1z, ys, vx, vy, vz);
    __builtin_amdgcn_sched_barrier(0);

    si_norm16_p(ys, vx, vy, vz);
    tv_norm16_p(ys, vx, vy, vz);
    __builtin_amdgcn_sched_barrier(0);

    v2f zs[8], zx[8], zy[8], zz[8];
    l2_chunk<0>(Wl, ys, vx, vy, vz, zs, zx, zy, zz);
    __builtin_amdgcn_sched_barrier(0);
    l2_chunk<4>(Wl, ys, vx, vy, vz, zs, zx, zy, zz);
    __builtin_amdgcn_sched_barrier(0);

    si_norm8_p(zs, zx, zy, zz);

    float oA[32], oB[32];
#pragma unroll
    for (int w = 0; w < 8; ++w) {
        oA[w] = 1.f / (1.f + __expf(-zs[w].x));
        oB[w] = 1.f / (1.f + __expf(-zs[w].y));
    }
#pragma unroll
    for (int w = 0; w < 8; ++w) {
        oA[8+3*w+0] = zx[w].x; oA[8+3*w+1] = zy[w].x; oA[8+3*w+2] = zz[w].x;
        oB[8+3*w+0] = zx[w].y; oB[8+3*w+1] = zy[w].y; oB[8+3*w+2] = zz[w].y;
    }
    float4* oa = reinterpret_cast<float4*>(out + (size_t)rA * 32);
    float4* ob = reinterpret_cast<float4*>(out + (size_t)rB * 32);
#pragma unroll
    for (int i = 0; i < 8; ++i) {
        oa[i] = make_float4(oA[4*i+0], oA[4*i+1], oA[4*i+2], oA[4*i+3]);
        ob[i] = make_float4(oB[4*i+0], oB[4*i+1], oB[4*i+2], oB[4*i+3]);
    }
}

extern "C" void kernel_launch(void* const* d_in, const int* in_sizes, int n_in,
                              void* d_out, int out_size, void* d_ws, size_t ws_size,
                              hipStream_t stream)
{
    const float* x = (const float*)d_in[0];
    float* ws = (float*)d_ws;
    prep_kernel<<<31, 256, 0, stream>>>(
        (const float*)d_in[1], (const float*)d_in[2], (const float*)d_in[3],
        (const float*)d_in[4], (const float*)d_in[5],
        (const float*)d_in[6], (const float*)d_in[7], (const float*)d_in[8],
        (const float*)d_in[9], (const float*)d_in[10], ws);
    DoubleLayer_main_kernel<<<NBROWS/512, 256, 0, stream>>>(x, ws, (float*)d_out);
}

// Round 8
// 251.826 us; speedup vs baseline: 2.6788x; 2.6788x over previous
//
#include <hip/hip_runtime.h>
#include <math.h>

#define NBROWS 262144

typedef float v2f __attribute__((ext_vector_type(2)));
__device__ __forceinline__ v2f pkset(float a, float b){ v2f r; r.x=a; r.y=b; return r; }
__device__ __forceinline__ v2f sp(float a){ return pkset(a,a); }

// ---- forced packed fp32 math (VOP3P, R7-proven syntax) ----
__device__ __forceinline__ void fma2(v2f& d, v2f a, v2f b){         // d += a*b
    asm("v_pk_fma_f32 %0, %1, %2, %0" : "+v"(d) : "v"(a), "v"(b));
}
__device__ __forceinline__ void fma2n(v2f& d, v2f a, v2f b){        // d -= a*b
    asm("v_pk_fma_f32 %0, %1, %2, %0 neg_lo:[1,0,0] neg_hi:[1,0,0]" : "+v"(d) : "v"(a), "v"(b));
}
__device__ __forceinline__ v2f mul2(v2f a, v2f b){
    v2f d; asm("v_pk_mul_f32 %0, %1, %2" : "=v"(d) : "v"(a), "v"(b)); return d;
}

// ---------------- packed d_ws layout (floats) — same as R6/R7 ----------------
// P1 [0,1152):     36 pairs (u<=v) x 32: [Sss w0..15][Svv0 w0..15]
// C1 [1152,2176):  (vv*8+u)*16 + w
// A1 [2176,2624):  28 pairs (u<v) x 16
// P2 [2624,4800):  136 pairs (u<=v) x 16: [Sss w0..7][Svv0 w0..7]
// C2 [4800,6848):  (vv*16+u)*8 + w
// A2 [6848,7808):  120 pairs (u<v) x 8
#define WS_TOT 7808

__device__ void pair_le(int p, int M, int& u, int& v) {
    u = 0; int cnt = M;
    while (p >= cnt) { p -= cnt; ++u; cnt = M - u; }
    v = u + p;
}
__device__ void pair_lt(int p, int M, int& u, int& v) {
    u = 0; int cnt = M - 1;
    while (p >= cnt) { p -= cnt; ++u; cnt = M - 1 - u; }
    v = u + 1 + p;
}

__global__ __launch_bounds__(256) void prep_kernel(
    const float* __restrict__ w1_ss, const float* __restrict__ w1_vv0,
    const float* __restrict__ w1_sv, const float* __restrict__ w1_vs,
    const float* __restrict__ w1_vv1,
    const float* __restrict__ w2_ss, const float* __restrict__ w2_vv0,
    const float* __restrict__ w2_sv, const float* __restrict__ w2_vs,
    const float* __restrict__ w2_vv1,
    float* __restrict__ ws)
{
    const float inv3 = 0.5773502691896258f;
    const float inv6 = 0.4082482904638631f;
    int i = blockIdx.x * 256 + threadIdx.x;
    if (i >= WS_TOT) return;
    float val = 0.f;
    if (i < 1152) {                       // P1
        int p = i >> 5, r = i & 31;
        int which = r >> 4, w = r & 15;
        int u, v; pair_le(p, 8, u, v);
        const float c0 = 0.08838834764831845f;
        const float* src = which ? w1_vv0 : w1_ss;
        float cc = which ? c0 * inv3 : c0;
        val = (u == v) ? cc * src[(u*8+v)*16+w]
                       : cc * (src[(u*8+v)*16+w] + src[(v*8+u)*16+w]);
    } else if (i < 2176) {                // C1
        int r = i - 1152; int vv = r >> 7, rem = r & 127, u = rem >> 4, w = rem & 15;
        val = (0.125f * inv3) * (w1_sv[(u*8+vv)*16+w] + w1_vs[(vv*8+u)*16+w]);
    } else if (i < 2624) {                // A1
        int r = i - 2176; int p = r >> 4, w = r & 15;
        int u, v; pair_lt(p, 8, u, v);
        val = (0.125f * inv6) * (w1_vv1[(u*8+v)*16+w] - w1_vv1[(v*8+u)*16+w]);
    } else if (i < 4800) {                // P2
        int r = i - 2624; int p = r >> 4, rr = r & 15, which = rr >> 3, w = rr & 7;
        int u, v; pair_le(p, 16, u, v);
        const float c0 = 0.04419417382415922f;
        const float* src = which ? w2_vv0 : w2_ss;
        float cc = which ? c0 * inv3 : c0;
        val = (u == v) ? cc * src[(u*16+v)*8+w]
                       : cc * (src[(u*16+v)*8+w] + src[(v*16+u)*8+w]);
    } else if (i < 6848) {                // C2
        int r = i - 4800; int vv = r >> 7, rem = r & 127, u = rem >> 3, w = rem & 7;
        val = (0.0625f * inv3) * (w2_sv[(u*16+vv)*8+w] + w2_vs[(vv*16+u)*8+w]);
    } else {                              // A2
        int r = i - 6848; int p = r >> 3, w = r & 7;
        int u, v; pair_lt(p, 16, u, v);
        val = (0.0625f * inv6) * (w2_vv1[(u*16+v)*8+w] - w2_vv1[(v*16+u)*8+w]);
    }
    ws[i] = val;
}

// ---------------- layer 1: 8 -> 16, chunk of 8 w (4 v2f per quantity) --------
// Inputs duplicated (both halves equal) -> features computed packed, each b64
// weight read feeds exactly one v_pk_fma. Accumulators pack over w-pairs.
template<int W0>
__device__ __forceinline__ void l1_chunk(const float* Wl,
    const v2f (&sd)[8], const v2f (&xd)[8], const v2f (&yd)[8], const v2f (&zd)[8],
    v2f (&ys)[8], v2f (&ox)[8], v2f (&oy)[8], v2f (&oz)[8])
{
    const int J0 = W0 / 2;
#pragma unroll
    for (int j = 0; j < 4; ++j) { ys[J0+j]=sp(0.f); ox[J0+j]=sp(0.f); oy[J0+j]=sp(0.f); oz[J0+j]=sp(0.f); }
    {   // symmetric ss + vv0
        int p = 0;
#pragma unroll
        for (int u = 0; u < 8; ++u)
#pragma unroll
        for (int vv = u; vv < 8; ++vv) {
            v2f pp = mul2(sd[u], sd[vv]);
            v2f dd = mul2(xd[u], xd[vv]); fma2(dd, yd[u], yd[vv]); fma2(dd, zd[u], zd[vv]);
            const v2f* qa = reinterpret_cast<const v2f*>(Wl + p*32 + W0);
            const v2f* qb = reinterpret_cast<const v2f*>(Wl + p*32 + 16 + W0);
#pragma unroll
            for (int j = 0; j < 4; ++j) { fma2(ys[J0+j], pp, qa[j]); fma2(ys[J0+j], dd, qb[j]); }
            ++p;
        }
    }
    // combined sv+vs
#pragma unroll
    for (int vv = 0; vv < 8; ++vv) {
        v2f tw[4];
#pragma unroll
        for (int j = 0; j < 4; ++j) tw[j] = sp(0.f);
#pragma unroll
        for (int u = 0; u < 8; ++u) {
            const v2f* qc = reinterpret_cast<const v2f*>(Wl + 1152 + (vv*8+u)*16 + W0);
#pragma unroll
            for (int j = 0; j < 4; ++j) fma2(tw[j], sd[u], qc[j]);
        }
#pragma unroll
        for (int j = 0; j < 4; ++j) {
            fma2(ox[J0+j], tw[j], xd[vv]);
            fma2(oy[J0+j], tw[j], yd[vv]);
            fma2(oz[J0+j], tw[j], zd[vv]);
        }
    }
    {   // antisymmetric cross
        int p = 0;
#pragma unroll
        for (int u = 0; u < 8; ++u)
#pragma unroll
        for (int vv = u + 1; vv < 8; ++vv) {
            v2f cx = mul2(yd[u], zd[vv]); fma2n(cx, zd[u], yd[vv]);
            v2f cy = mul2(zd[u], xd[vv]); fma2n(cy, xd[u], zd[vv]);
            v2f cz = mul2(xd[u], yd[vv]); fma2n(cz, yd[u], xd[vv]);
            const v2f* qa = reinterpret_cast<const v2f*>(Wl + 2176 + p*16 + W0);
#pragma unroll
            for (int j = 0; j < 4; ++j) {
                v2f a = qa[j];
                fma2(ox[J0+j], cx, a); fma2(oy[J0+j], cy, a); fma2(oz[J0+j], cz, a);
            }
            ++p;
        }
    }
}

// ---------------- layer 2: 16 -> 8, single pass (4 v2f per quantity) --------
__device__ __forceinline__ void l2_pass(const float* Wl,
    const v2f (&sd)[16], const v2f (&xd)[16], const v2f (&yd)[16], const v2f (&zd)[16],
    v2f (&zs)[4], v2f (&zx)[4], v2f (&zy)[4], v2f (&zz)[4])
{
#pragma unroll
    for (int j = 0; j < 4; ++j) { zs[j]=sp(0.f); zx[j]=sp(0.f); zy[j]=sp(0.f); zz[j]=sp(0.f); }
    {   // symmetric
        int p = 0;
#pragma unroll
        for (int u = 0; u < 16; ++u)
#pragma unroll
        for (int vv = u; vv < 16; ++vv) {
            v2f pp = mul2(sd[u], sd[vv]);
            v2f dd = mul2(xd[u], xd[vv]); fma2(dd, yd[u], yd[vv]); fma2(dd, zd[u], zd[vv]);
            const v2f* qa = reinterpret_cast<const v2f*>(Wl + 2624 + p*16);
            const v2f* qb = reinterpret_cast<const v2f*>(Wl + 2624 + p*16 + 8);
#pragma unroll
            for (int j = 0; j < 4; ++j) { fma2(zs[j], pp, qa[j]); fma2(zs[j], dd, qb[j]); }
            ++p;
        }
    }
#pragma unroll
    for (int vv = 0; vv < 16; ++vv) {
        v2f tw[4];
#pragma unroll
        for (int j = 0; j < 4; ++j) tw[j] = sp(0.f);
#pragma unroll
        for (int u = 0; u < 16; ++u) {
            const v2f* qc = reinterpret_cast<const v2f*>(Wl + 4800 + (vv*16+u)*8);
#pragma unroll
            for (int j = 0; j < 4; ++j) fma2(tw[j], sd[u], qc[j]);
        }
#pragma unroll
        for (int j = 0; j < 4; ++j) {
            fma2(zx[j], tw[j], xd[vv]);
            fma2(zy[j], tw[j], yd[vv]);
            fma2(zz[j], tw[j], zd[vv]);
        }
    }
    {   // cross
        int p = 0;
#pragma unroll
        for (int u = 0; u < 16; ++u)
#pragma unroll
        for (int vv = u + 1; vv < 16; ++vv) {
            v2f cx = mul2(yd[u], zd[vv]); fma2n(cx, zd[u], yd[vv]);
            v2f cy = mul2(zd[u], xd[vv]); fma2n(cy, xd[u], zd[vv]);
            v2f cz = mul2(xd[u], yd[vv]); fma2n(cz, yd[u], xd[vv]);
            const v2f* qa = reinterpret_cast<const v2f*>(Wl + 6848 + p*8);
#pragma unroll
            for (int j = 0; j < 4; ++j) {
                v2f a = qa[j];
                fma2(zx[j], cx, a); fma2(zy[j], cy, a); fma2(zz[j], cz, a);
            }
            ++p;
        }
    }
}

// ---------------- norms over w-pair-packed accumulators (R6-proven) ---------
__device__ __forceinline__ void si_norm16_v(v2f (&ys)[8], v2f (&ox)[8], v2f (&oy)[8], v2f (&oz)[8])
{
    v2f a = sp(0.f);
#pragma unroll
    for (int j = 0; j < 8; ++j) a += ys[j];
    float m = (a.x + a.y) * (1.f/16);
    v2f vr = sp(0.f);
#pragma unroll
    for (int j = 0; j < 8; ++j) { v2f d = ys[j] - sp(m); vr += d*d; }
    float inv = 1.f / (sqrtf((vr.x+vr.y) * (1.f/15)) + 1e-9f);
#pragma unroll
    for (int j = 0; j < 8; ++j) ys[j] *= sp(inv);

    float n1[16]; float sum = 0.f;
#pragma unroll
    for (int j = 0; j < 8; ++j) {
        v2f nn = ox[j]*ox[j] + oy[j]*oy[j] + oz[j]*oz[j];
        n1[2*j]   = sqrtf(nn.x + 1e-9f);
        n1[2*j+1] = sqrtf(nn.y + 1e-9f);
        sum += n1[2*j] + n1[2*j+1];
    }
    float mn = sum * (1.f/16);
    float var = 0.f;
#pragma unroll
    for (int i = 0; i < 16; ++i) { float d = n1[i] - mn; var += d*d; }
    float invv = 1.f / (sqrtf(var * (1.f/15)) + 1e-9f);
    v2f vi = sp(invv);
#pragma unroll
    for (int j = 0; j < 8; ++j) { ox[j] *= vi; oy[j] *= vi; oz[j] *= vi; }
}

__device__ __forceinline__ void tv_norm16_v(v2f (&ys)[8], v2f (&ox)[8], v2f (&oy)[8], v2f (&oz)[8])
{
    v2f ssum = sp(0.f);
#pragma unroll
    for (int j = 0; j < 8; ++j) ssum += ys[j]*ys[j];
    float inv = 1.f / sqrtf(ssum.x + ssum.y + 1e-6f);
#pragma unroll
    for (int j = 0; j < 8; ++j) ys[j] *= sp(inv);

    v2f sx = sp(0.f), sy = sp(0.f), sz = sp(0.f);
#pragma unroll
    for (int j = 0; j < 8; ++j) { sx += ox[j]*ox[j]; sy += oy[j]*oy[j]; sz += oz[j]*oz[j]; }
    float nm = (sqrtf(sx.x+sx.y+1e-6f) + sqrtf(sy.x+sy.y+1e-6f) + sqrtf(sz.x+sz.y+1e-6f)) * (1.f/3.f);
    float invv = 1.f / (nm + 1e-6f);
#pragma unroll
    for (int j = 0; j < 8; ++j) { ox[j] *= sp(invv); oy[j] *= sp(invv); oz[j] *= sp(invv); }
}

__device__ __forceinline__ void si_norm8_v(v2f (&zs)[4], v2f (&zx)[4], v2f (&zy)[4], v2f (&zz)[4])
{
    v2f a = sp(0.f);
#pragma unroll
    for (int j = 0; j < 4; ++j) a += zs[j];
    float m = (a.x + a.y) * (1.f/8);
    v2f vr = sp(0.f);
#pragma unroll
    for (int j = 0; j < 4; ++j) { v2f d = zs[j] - sp(m); vr += d*d; }
    float inv = 1.f / (sqrtf((vr.x+vr.y) * (1.f/7)) + 1e-9f);
#pragma unroll
    for (int j = 0; j < 4; ++j) zs[j] *= sp(inv);

    float n1[8]; float sum = 0.f;
#pragma unroll
    for (int j = 0; j < 4; ++j) {
        v2f nn = zx[j]*zx[j] + zy[j]*zy[j] + zz[j]*zz[j];
        n1[2*j]   = sqrtf(nn.x + 1e-9f);
        n1[2*j+1] = sqrtf(nn.y + 1e-9f);
        sum += n1[2*j] + n1[2*j+1];
    }
    float mn = sum * (1.f/8);
    float var = 0.f;
#pragma unroll
    for (int i = 0; i < 8; ++i) { float d = n1[i] - mn; var += d*d; }
    float invv = 1.f / (sqrtf(var * (1.f/7)) + 1e-9f);
    v2f vi = sp(invv);
#pragma unroll
    for (int j = 0; j < 4; ++j) { zx[j] *= vi; zy[j] *= vi; zz[j] *= vi; }
}

__device__ __forceinline__ float fast_tanh(float x) {
    return 1.f - 2.f / (__expf(2.f * x) + 1.f);
}

// 1 row/thread (R7: 2-row packing spills). v2f packs over w-pairs (R6 axis).
// Packed FMAs forced via asm (R6: clang scalarized C-level v2f). b64-max
// weight reads (R5). Chunk+fence skeleton (R4/R6). __launch_bounds__(256)
// only (R2: min-waves clause causes wholesale scratch demotion).
__global__ __launch_bounds__(256) void DoubleLayer_main_kernel(
    const float* __restrict__ x,
    const float* __restrict__ ws,
    float* __restrict__ out)
{
    __shared__ float Wl[WS_TOT];

    int t = threadIdx.x;
    int row = blockIdx.x * 256 + t;
    const float4* xr = reinterpret_cast<const float4*>(x + (size_t)row * 32);
    float4 q0 = xr[0], q1 = xr[1], q2 = xr[2], q3 = xr[3];
    float4 q4 = xr[4], q5 = xr[5], q6 = xr[6], q7 = xr[7];

    // stage packed weights: 1952 float4
#pragma unroll
    for (int i = 0; i < 8; ++i) {
        int idx = t + i * 256;
        if (idx < WS_TOT/4)
            reinterpret_cast<float4*>(Wl)[idx] = reinterpret_cast<const float4*>(ws)[idx];
    }
    __syncthreads();

    // duplicated inputs: both v2f halves equal -> packed feature math
    v2f sd[8], xd[8], yd[8], zd[8];
    sd[0]=sp(fast_tanh(q0.x)); sd[1]=sp(fast_tanh(q0.y)); sd[2]=sp(fast_tanh(q0.z)); sd[3]=sp(fast_tanh(q0.w));
    sd[4]=sp(fast_tanh(q1.x)); sd[5]=sp(fast_tanh(q1.y)); sd[6]=sp(fast_tanh(q1.z)); sd[7]=sp(fast_tanh(q1.w));
    xd[0]=sp(q2.x); yd[0]=sp(q2.y); zd[0]=sp(q2.z);
    xd[1]=sp(q2.w); yd[1]=sp(q3.x); zd[1]=sp(q3.y);
    xd[2]=sp(q3.z); yd[2]=sp(q3.w); zd[2]=sp(q4.x);
    xd[3]=sp(q4.y); yd[3]=sp(q4.z); zd[3]=sp(q4.w);
    xd[4]=sp(q5.x); yd[4]=sp(q5.y); zd[4]=sp(q5.z);
    xd[5]=sp(q5.w); yd[5]=sp(q6.x); zd[5]=sp(q6.y);
    xd[6]=sp(q6.z); yd[6]=sp(q6.w); zd[6]=sp(q7.x);
    xd[7]=sp(q7.y); yd[7]=sp(q7.z); zd[7]=sp(q7.w);

    v2f ys[8], ox[8], oy[8], oz[8];
    l1_chunk<0>(Wl, sd, xd, yd, zd, ys, ox, oy, oz);
    __builtin_amdgcn_sched_barrier(0);
    l1_chunk<8>(Wl, sd, xd, yd, zd, ys, ox, oy, oz);
    __builtin_amdgcn_sched_barrier(0);

    si_norm16_v(ys, ox, oy, oz);
    tv_norm16_v(ys, ox, oy, oz);
    __builtin_amdgcn_sched_barrier(0);

    // unpack w-pair-packed layer-1 outputs into duplicated per-channel inputs
    v2f s2d[16], x2d[16], y2d[16], z2d[16];
#pragma unroll
    for (int j = 0; j < 8; ++j) {
        s2d[2*j] = sp(ys[j].x); s2d[2*j+1] = sp(ys[j].y);
        x2d[2*j] = sp(ox[j].x); x2d[2*j+1] = sp(ox[j].y);
        y2d[2*j] = sp(oy[j].x); y2d[2*j+1] = sp(oy[j].y);
        z2d[2*j] = sp(oz[j].x); z2d[2*j+1] = sp(oz[j].y);
    }
    __builtin_amdgcn_sched_barrier(0);

    v2f zs[4], zx[4], zy[4], zz[4];
    l2_pass(Wl, s2d, x2d, y2d, z2d, zs, zx, zy, zz);
    __builtin_amdgcn_sched_barrier(0);

    si_norm8_v(zs, zx, zy, zz);

    float o[32];
#pragma unroll
    for (int j = 0; j < 4; ++j) {
        o[2*j]   = 1.f / (1.f + __expf(-zs[j].x));
        o[2*j+1] = 1.f / (1.f + __expf(-zs[j].y));
    }
#pragma unroll
    for (int j = 0; j < 4; ++j) {
        int w0 = 2*j, w1 = 2*j+1;
        o[8+3*w0+0] = zx[j].x; o[8+3*w0+1] = zy[j].x; o[8+3*w0+2] = zz[j].x;
        o[8+3*w1+0] = zx[j].y; o[8+3*w1+1] = zy[j].y; o[8+3*w1+2] = zz[j].y;
    }
    float4* orow = reinterpret_cast<float4*>(out + (size_t)row * 32);
#pragma unroll
    for (int i = 0; i < 8; ++i) orow[i] = make_float4(o[4*i+0], o[4*i+1], o[4*i+2], o[4*i+3]);
}

extern "C" void kernel_launch(void* const* d_in, const int* in_sizes, int n_in,
                              void* d_out, int out_size, void* d_ws, size_t ws_size,
                              hipStream_t stream)
{
    const float* x = (const float*)d_in[0];
    float* ws = (float*)d_ws;
    prep_kernel<<<31, 256, 0, stream>>>(
        (const float*)d_in[1], (const float*)d_in[2], (const float*)d_in[3],
        (const float*)d_in[4], (const float*)d_in[5],
        (const float*)d_in[6], (const float*)d_in[7], (const float*)d_in[8],
        (const float*)d_in[9], (const float*)d_in[10], ws);
    DoubleLayer_main_kernel<<<NBROWS/256, 256, 0, stream>>>(x, ws, (float*)d_out);
}

// Round 9
// 222.038 us; speedup vs baseline: 3.0382x; 1.1342x over previous
//
#include <hip/hip_runtime.h>
#include <hip/hip_fp16.h>
#include <math.h>

#define NBROWS 262144

typedef float v2f __attribute__((ext_vector_type(2)));
__device__ __forceinline__ v2f pkset(float a, float b){ v2f r; r.x=a; r.y=b; return r; }
__device__ __forceinline__ v2f sp(float a){ return pkset(a,a); }

__device__ __forceinline__ unsigned pack_h2(v2f a){
    __half2 h = __floats2half2_rn(a.x, a.y);
    unsigned u; __builtin_memcpy(&u, &h, 4); return u;
}
__device__ __forceinline__ float2 unpack_h2(unsigned u){
    __half2 h; __builtin_memcpy(&h, &u, 4);
    return __half22float2(h);
}

// ---------------- packed d_ws layout (floats) — R6-proven ----------------
// P1 [0,1152):     36 pairs (u<=v) x 32: [Sss w0..15][Svv0 w0..15]
// C1 [1152,2176):  (vv*8+u)*16 + w
// A1 [2176,2624):  28 pairs (u<v) x 16
// P2 [2624,4800):  136 pairs (u<=v) x 16: [Sss w0..7][Svv0 w0..7]
// C2 [4800,6848):  (vv*16+u)*8 + w
// A2 [6848,7808):  120 pairs (u<v) x 8
#define WS_TOT 7808

__device__ void pair_le(int p, int M, int& u, int& v) {
    u = 0; int cnt = M;
    while (p >= cnt) { p -= cnt; ++u; cnt = M - u; }
    v = u + p;
}
__device__ void pair_lt(int p, int M, int& u, int& v) {
    u = 0; int cnt = M - 1;
    while (p >= cnt) { p -= cnt; ++u; cnt = M - 1 - u; }
    v = u + 1 + p;
}

__global__ __launch_bounds__(256) void prep_kernel(
    const float* __restrict__ w1_ss, const float* __restrict__ w1_vv0,
    const float* __restrict__ w1_sv, const float* __restrict__ w1_vs,
    const float* __restrict__ w1_vv1,
    const float* __restrict__ w2_ss, const float* __restrict__ w2_vv0,
    const float* __restrict__ w2_sv, const float* __restrict__ w2_vs,
    const float* __restrict__ w2_vv1,
    float* __restrict__ ws)
{
    const float inv3 = 0.5773502691896258f;
    const float inv6 = 0.4082482904638631f;
    int i = blockIdx.x * 256 + threadIdx.x;
    if (i >= WS_TOT) return;
    float val = 0.f;
    if (i < 1152) {                       // P1
        int p = i >> 5, r = i & 31;
        int which = r >> 4, w = r & 15;
        int u, v; pair_le(p, 8, u, v);
        const float c0 = 0.08838834764831845f;
        const float* src = which ? w1_vv0 : w1_ss;
        float cc = which ? c0 * inv3 : c0;
        val = (u == v) ? cc * src[(u*8+v)*16+w]
                       : cc * (src[(u*8+v)*16+w] + src[(v*8+u)*16+w]);
    } else if (i < 2176) {                // C1
        int r = i - 1152; int vv = r >> 7, rem = r & 127, u = rem >> 4, w = rem & 15;
        val = (0.125f * inv3) * (w1_sv[(u*8+vv)*16+w] + w1_vs[(vv*8+u)*16+w]);
    } else if (i < 2624) {                // A1
        int r = i - 2176; int p = r >> 4, w = r & 15;
        int u, v; pair_lt(p, 8, u, v);
        val = (0.125f * inv6) * (w1_vv1[(u*8+v)*16+w] - w1_vv1[(v*8+u)*16+w]);
    } else if (i < 4800) {                // P2
        int r = i - 2624; int p = r >> 4, rr = r & 15, which = rr >> 3, w = rr & 7;
        int u, v; pair_le(p, 16, u, v);
        const float c0 = 0.04419417382415922f;
        const float* src = which ? w2_vv0 : w2_ss;
        float cc = which ? c0 * inv3 : c0;
        val = (u == v) ? cc * src[(u*16+v)*8+w]
                       : cc * (src[(u*16+v)*8+w] + src[(v*16+u)*8+w]);
    } else if (i < 6848) {                // C2
        int r = i - 4800; int vv = r >> 7, rem = r & 127, u = rem >> 3, w = rem & 7;
        val = (0.0625f * inv3) * (w2_sv[(u*16+vv)*8+w] + w2_vs[(vv*16+u)*8+w]);
    } else {                              // A2
        int r = i - 6848; int p = r >> 3, w = r & 7;
        int u, v; pair_lt(p, 16, u, v);
        val = (0.0625f * inv6) * (w2_vv1[(u*16+v)*8+w] - w2_vv1[(v*16+u)*8+w]);
    }
    ws[i] = val;
}

// ---------------- layer 1: 8 -> 16, chunk of 8 outputs (R6-proven) ----------
template<int W0>
__device__ __forceinline__ void l1_chunk(const float* Wl,
    const float (&s)[8], const float (&v)[8][3],
    v2f (&ys)[8], v2f (&ox)[8], v2f (&oy)[8], v2f (&oz)[8])
{
    const int J0 = W0 / 2;
#pragma unroll
    for (int j = 0; j < 4; ++j) { ys[J0+j]=sp(0.f); ox[J0+j]=sp(0.f); oy[J0+j]=sp(0.f); oz[J0+j]=sp(0.f); }
    {   // symmetric ss + vv0
        int p = 0;
#pragma unroll
        for (int u = 0; u < 8; ++u)
#pragma unroll
        for (int vv = u; vv < 8; ++vv) {
            float pp = s[u] * s[vv];
            float dd = v[u][0]*v[vv][0] + v[u][1]*v[vv][1] + v[u][2]*v[vv][2];
            const v2f* qa = reinterpret_cast<const v2f*>(Wl + p*32 + W0);
            const v2f* qb = reinterpret_cast<const v2f*>(Wl + p*32 + 16 + W0);
            v2f vp = sp(pp), vd = sp(dd);
#pragma unroll
            for (int j = 0; j < 4; ++j) ys[J0+j] += vp*qa[j] + vd*qb[j];
            ++p;
        }
    }
    // combined sv+vs
#pragma unroll
    for (int vv = 0; vv < 8; ++vv) {
        v2f tw[4];
#pragma unroll
        for (int j = 0; j < 4; ++j) tw[j] = sp(0.f);
#pragma unroll
        for (int u = 0; u < 8; ++u) {
            const v2f* qc = reinterpret_cast<const v2f*>(Wl + 1152 + (vv*8+u)*16 + W0);
            v2f su = sp(s[u]);
#pragma unroll
            for (int j = 0; j < 4; ++j) tw[j] += su*qc[j];
        }
        v2f vx = sp(v[vv][0]), vy = sp(v[vv][1]), vz = sp(v[vv][2]);
#pragma unroll
        for (int j = 0; j < 4; ++j) {
            ox[J0+j] += tw[j]*vx; oy[J0+j] += tw[j]*vy; oz[J0+j] += tw[j]*vz;
        }
    }
    {   // antisymmetric cross
        int p = 0;
#pragma unroll
        for (int u = 0; u < 8; ++u)
#pragma unroll
        for (int vv = u + 1; vv < 8; ++vv) {
            float cx = v[u][1]*v[vv][2] - v[u][2]*v[vv][1];
            float cy = v[u][2]*v[vv][0] - v[u][0]*v[vv][2];
            float cz = v[u][0]*v[vv][1] - v[u][1]*v[vv][0];
            const v2f* qa = reinterpret_cast<const v2f*>(Wl + 2176 + p*16 + W0);
            v2f vcx = sp(cx), vcy = sp(cy), vcz = sp(cz);
#pragma unroll
            for (int j = 0; j < 4; ++j) {
                v2f a = qa[j];
                ox[J0+j] += vcx*a; oy[J0+j] += vcy*a; oz[J0+j] += vcz*a;
            }
            ++p;
        }
    }
}

// ---------------- layer 2: 16 -> 8, single pass; LDS offsets rebased --------
// P2 at 0, C2 at 2176, A2 at 4224 (LDS holds ws[2624..7808))
__device__ __forceinline__ void l2_pass(const float* Wl,
    const float (&s)[16], const float (&v)[16][3],
    v2f (&zs)[4], v2f (&zx)[4], v2f (&zy)[4], v2f (&zz)[4])
{
#pragma unroll
    for (int j = 0; j < 4; ++j) { zs[j]=sp(0.f); zx[j]=sp(0.f); zy[j]=sp(0.f); zz[j]=sp(0.f); }
    {   // symmetric
        int p = 0;
#pragma unroll
        for (int u = 0; u < 16; ++u)
#pragma unroll
        for (int vv = u; vv < 16; ++vv) {
            float pp = s[u] * s[vv];
            float dd = v[u][0]*v[vv][0] + v[u][1]*v[vv][1] + v[u][2]*v[vv][2];
            const v2f* qa = reinterpret_cast<const v2f*>(Wl + p*16);
            const v2f* qb = reinterpret_cast<const v2f*>(Wl + p*16 + 8);
            v2f vp = sp(pp), vd = sp(dd);
#pragma unroll
            for (int j = 0; j < 4; ++j) zs[j] += vp*qa[j] + vd*qb[j];
            ++p;
        }
    }
#pragma unroll
    for (int vv = 0; vv < 16; ++vv) {
        v2f tw[4];
#pragma unroll
        for (int j = 0; j < 4; ++j) tw[j] = sp(0.f);
#pragma unroll
        for (int u = 0; u < 16; ++u) {
            const v2f* qc = reinterpret_cast<const v2f*>(Wl + 2176 + (vv*16+u)*8);
            v2f su = sp(s[u]);
#pragma unroll
            for (int j = 0; j < 4; ++j) tw[j] += su*qc[j];
        }
        v2f vx = sp(v[vv][0]), vy = sp(v[vv][1]), vz = sp(v[vv][2]);
#pragma unroll
        for (int j = 0; j < 4; ++j) {
            zx[j] += tw[j]*vx; zy[j] += tw[j]*vy; zz[j] += tw[j]*vz;
        }
    }
    {   // cross
        int p = 0;
#pragma unroll
        for (int u = 0; u < 16; ++u)
#pragma unroll
        for (int vv = u + 1; vv < 16; ++vv) {
            float cx = v[u][1]*v[vv][2] - v[u][2]*v[vv][1];
            float cy = v[u][2]*v[vv][0] - v[u][0]*v[vv][2];
            float cz = v[u][0]*v[vv][1] - v[u][1]*v[vv][0];
            const v2f* qa = reinterpret_cast<const v2f*>(Wl + 4224 + p*8);
            v2f vcx = sp(cx), vcy = sp(cy), vcz = sp(cz);
#pragma unroll
            for (int j = 0; j < 4; ++j) {
                v2f a = qa[j];
                zx[j] += vcx*a; zy[j] += vcy*a; zz[j] += vcz*a;
            }
            ++p;
        }
    }
}

// ---------------- norms (R6-proven) ----------------
__device__ __forceinline__ void si_norm16_v(v2f (&ys)[8], v2f (&ox)[8], v2f (&oy)[8], v2f (&oz)[8])
{
    v2f a = sp(0.f);
#pragma unroll
    for (int j = 0; j < 8; ++j) a += ys[j];
    float m = (a.x + a.y) * (1.f/16);
    v2f vr = sp(0.f);
#pragma unroll
    for (int j = 0; j < 8; ++j) { v2f d = ys[j] - sp(m); vr += d*d; }
    float inv = 1.f / (sqrtf((vr.x+vr.y) * (1.f/15)) + 1e-9f);
#pragma unroll
    for (int j = 0; j < 8; ++j) ys[j] *= sp(inv);

    float n1[16]; float sum = 0.f;
#pragma unroll
    for (int j = 0; j < 8; ++j) {
        v2f nn = ox[j]*ox[j] + oy[j]*oy[j] + oz[j]*oz[j];
        n1[2*j]   = sqrtf(nn.x + 1e-9f);
        n1[2*j+1] = sqrtf(nn.y + 1e-9f);
        sum += n1[2*j] + n1[2*j+1];
    }
    float mn = sum * (1.f/16);
    float var = 0.f;
#pragma unroll
    for (int i = 0; i < 16; ++i) { float d = n1[i] - mn; var += d*d; }
    float invv = 1.f / (sqrtf(var * (1.f/15)) + 1e-9f);
    v2f vi = sp(invv);
#pragma unroll
    for (int j = 0; j < 8; ++j) { ox[j] *= vi; oy[j] *= vi; oz[j] *= vi; }
}

__device__ __forceinline__ void tv_norm16_v(v2f (&ys)[8], v2f (&ox)[8], v2f (&oy)[8], v2f (&oz)[8])
{
    v2f ssum = sp(0.f);
#pragma unroll
    for (int j = 0; j < 8; ++j) ssum += ys[j]*ys[j];
    float inv = 1.f / sqrtf(ssum.x + ssum.y + 1e-6f);
#pragma unroll
    for (int j = 0; j < 8; ++j) ys[j] *= sp(inv);

    v2f sx = sp(0.f), sy = sp(0.f), sz = sp(0.f);
#pragma unroll
    for (int j = 0; j < 8; ++j) { sx += ox[j]*ox[j]; sy += oy[j]*oy[j]; sz += oz[j]*oz[j]; }
    float nm = (sqrtf(sx.x+sx.y+1e-6f) + sqrtf(sy.x+sy.y+1e-6f) + sqrtf(sz.x+sz.y+1e-6f)) * (1.f/3.f);
    float invv = 1.f / (nm + 1e-6f);
#pragma unroll
    for (int j = 0; j < 8; ++j) { ox[j] *= sp(invv); oy[j] *= sp(invv); oz[j] *= sp(invv); }
}

__device__ __forceinline__ void si_norm8_v(v2f (&zs)[4], v2f (&zx)[4], v2f (&zy)[4], v2f (&zz)[4])
{
    v2f a = sp(0.f);
#pragma unroll
    for (int j = 0; j < 4; ++j) a += zs[j];
    float m = (a.x + a.y) * (1.f/8);
    v2f vr = sp(0.f);
#pragma unroll
    for (int j = 0; j < 4; ++j) { v2f d = zs[j] - sp(m); vr += d*d; }
    float inv = 1.f / (sqrtf((vr.x+vr.y) * (1.f/7)) + 1e-9f);
#pragma unroll
    for (int j = 0; j < 4; ++j) zs[j] *= sp(inv);

    float n1[8]; float sum = 0.f;
#pragma unroll
    for (int j = 0; j < 4; ++j) {
        v2f nn = zx[j]*zx[j] + zy[j]*zy[j] + zz[j]*zz[j];
        n1[2*j]   = sqrtf(nn.x + 1e-9f);
        n1[2*j+1] = sqrtf(nn.y + 1e-9f);
        sum += n1[2*j] + n1[2*j+1];
    }
    float mn = sum * (1.f/8);
    float var = 0.f;
#pragma unroll
    for (int i = 0; i < 8; ++i) { float d = n1[i] - mn; var += d*d; }
    float invv = 1.f / (sqrtf(var * (1.f/7)) + 1e-9f);
    v2f vi = sp(invv);
#pragma unroll
    for (int j = 0; j < 4; ++j) { zx[j] *= vi; zy[j] *= vi; zz[j] *= vi; }
}

__device__ __forceinline__ float fast_tanh(float x) {
    return 1.f - 2.f / (__expf(2.f * x) + 1.f);
}

// ================= Kernel A: layer 1 + si_norm + tv_norm =====================
// Writes 64 f16 (= 128 B, the whole row) into d_out as scratch.
__global__ __launch_bounds__(256) void DoubleLayer_l1_kernel(
    const float* __restrict__ x,
    const float* __restrict__ ws,
    unsigned* __restrict__ inter)
{
    __shared__ float Wl[2624];

    int t = threadIdx.x;
    int row = blockIdx.x * 256 + t;
    const float4* xr = reinterpret_cast<const float4*>(x + (size_t)row * 32);
    float4 q0 = xr[0], q1 = xr[1], q2 = xr[2], q3 = xr[3];
    float4 q4 = xr[4], q5 = xr[5], q6 = xr[6], q7 = xr[7];

    // stage L1 weights: 656 float4
#pragma unroll
    for (int i = 0; i < 3; ++i) {
        int idx = t + i * 256;
        if (idx < 656)
            reinterpret_cast<float4*>(Wl)[idx] = reinterpret_cast<const float4*>(ws)[idx];
    }
    __syncthreads();

    float s1[8];
    s1[0] = fast_tanh(q0.x); s1[1] = fast_tanh(q0.y); s1[2] = fast_tanh(q0.z); s1[3] = fast_tanh(q0.w);
    s1[4] = fast_tanh(q1.x); s1[5] = fast_tanh(q1.y); s1[6] = fast_tanh(q1.z); s1[7] = fast_tanh(q1.w);
    float v1[8][3];
    v1[0][0]=q2.x; v1[0][1]=q2.y; v1[0][2]=q2.z;
    v1[1][0]=q2.w; v1[1][1]=q3.x; v1[1][2]=q3.y;
    v1[2][0]=q3.z; v1[2][1]=q3.w; v1[2][2]=q4.x;
    v1[3][0]=q4.y; v1[3][1]=q4.z; v1[3][2]=q4.w;
    v1[4][0]=q5.x; v1[4][1]=q5.y; v1[4][2]=q5.z;
    v1[5][0]=q5.w; v1[5][1]=q6.x; v1[5][2]=q6.y;
    v1[6][0]=q6.z; v1[6][1]=q6.w; v1[6][2]=q7.x;
    v1[7][0]=q7.y; v1[7][1]=q7.z; v1[7][2]=q7.w;

    v2f ys[8], ox[8], oy[8], oz[8];
    l1_chunk<0>(Wl, s1, v1, ys, ox, oy, oz);
    __builtin_amdgcn_sched_barrier(0);
    l1_chunk<8>(Wl, s1, v1, ys, ox, oy, oz);
    __builtin_amdgcn_sched_barrier(0);

    si_norm16_v(ys, ox, oy, oz);
    tv_norm16_v(ys, ox, oy, oz);

    // pack 64 f16: u[0..7]=ys, u[8..15]=ox, u[16..23]=oy, u[24..31]=oz
    unsigned* orow = inter + (size_t)row * 32;
    uint4* o4 = reinterpret_cast<uint4*>(orow);
#pragma unroll
    for (int j = 0; j < 2; ++j)
        o4[j] = make_uint4(pack_h2(ys[4*j]), pack_h2(ys[4*j+1]), pack_h2(ys[4*j+2]), pack_h2(ys[4*j+3]));
#pragma unroll
    for (int j = 0; j < 2; ++j)
        o4[2+j] = make_uint4(pack_h2(ox[4*j]), pack_h2(ox[4*j+1]), pack_h2(ox[4*j+2]), pack_h2(ox[4*j+3]));
#pragma unroll
    for (int j = 0; j < 2; ++j)
        o4[4+j] = make_uint4(pack_h2(oy[4*j]), pack_h2(oy[4*j+1]), pack_h2(oy[4*j+2]), pack_h2(oy[4*j+3]));
#pragma unroll
    for (int j = 0; j < 2; ++j)
        o4[6+j] = make_uint4(pack_h2(oz[4*j]), pack_h2(oz[4*j+1]), pack_h2(oz[4*j+2]), pack_h2(oz[4*j+3]));
}

// ================= Kernel B: layer 2 + si_norm + sigmoid =====================
// Reads the 64-f16 intermediate from d_out, overwrites with final 32 f32.
__global__ __launch_bounds__(256) void DoubleLayer_l2_kernel(
    const float* __restrict__ ws,
    float* __restrict__ out)
{
    __shared__ float Wl[5184];

    int t = threadIdx.x;
    int row = blockIdx.x * 256 + t;
    const uint4* irow = reinterpret_cast<const uint4*>(out + (size_t)row * 32);
    uint4 h0 = irow[0], h1 = irow[1], h2 = irow[2], h3 = irow[3];
    uint4 h4 = irow[4], h5 = irow[5], h6 = irow[6], h7 = irow[7];

    // stage L2 weights: ws[2624..7808) = 1296 float4
    const float4* wsrc = reinterpret_cast<const float4*>(ws + 2624);
#pragma unroll
    for (int i = 0; i < 6; ++i) {
        int idx = t + i * 256;
        if (idx < 1296)
            reinterpret_cast<float4*>(Wl)[idx] = wsrc[idx];
    }
    __syncthreads();

    float s2[16], vv2[16][3];
    {
        unsigned us[8] = {h0.x,h0.y,h0.z,h0.w,h1.x,h1.y,h1.z,h1.w};
        unsigned ux[8] = {h2.x,h2.y,h2.z,h2.w,h3.x,h3.y,h3.z,h3.w};
        unsigned uy[8] = {h4.x,h4.y,h4.z,h4.w,h5.x,h5.y,h5.z,h5.w};
        unsigned uz[8] = {h6.x,h6.y,h6.z,h6.w,h7.x,h7.y,h7.z,h7.w};
#pragma unroll
        for (int j = 0; j < 8; ++j) {
            float2 fs = unpack_h2(us[j]); s2[2*j] = fs.x; s2[2*j+1] = fs.y;
            float2 fx = unpack_h2(ux[j]); vv2[2*j][0] = fx.x; vv2[2*j+1][0] = fx.y;
            float2 fy = unpack_h2(uy[j]); vv2[2*j][1] = fy.x; vv2[2*j+1][1] = fy.y;
            float2 fz = unpack_h2(uz[j]); vv2[2*j][2] = fz.x; vv2[2*j+1][2] = fz.y;
        }
    }
    __builtin_amdgcn_sched_barrier(0);

    v2f zs[4], zx[4], zy[4], zz[4];
    l2_pass(Wl, s2, vv2, zs, zx, zy, zz);
    __builtin_amdgcn_sched_barrier(0);

    si_norm8_v(zs, zx, zy, zz);

    float o[32];
#pragma unroll
    for (int j = 0; j < 4; ++j) {
        o[2*j]   = 1.f / (1.f + __expf(-zs[j].x));
        o[2*j+1] = 1.f / (1.f + __expf(-zs[j].y));
    }
#pragma unroll
    for (int j = 0; j < 4; ++j) {
        int w0 = 2*j, w1 = 2*j+1;
        o[8+3*w0+0] = zx[j].x; o[8+3*w0+1] = zy[j].x; o[8+3*w0+2] = zz[j].x;
        o[8+3*w1+0] = zx[j].y; o[8+3*w1+1] = zy[j].y; o[8+3*w1+2] = zz[j].y;
    }
    float4* orow = reinterpret_cast<float4*>(out + (size_t)row * 32);
#pragma unroll
    for (int i = 0; i < 8; ++i) orow[i] = make_float4(o[4*i+0], o[4*i+1], o[4*i+2], o[4*i+3]);
}

extern "C" void kernel_launch(void* const* d_in, const int* in_sizes, int n_in,
                              void* d_out, int out_size, void* d_ws, size_t ws_size,
                              hipStream_t stream)
{
    const float* x = (const float*)d_in[0];
    float* ws = (float*)d_ws;
    prep_kernel<<<31, 256, 0, stream>>>(
        (const float*)d_in[1], (const float*)d_in[2], (const float*)d_in[3],
        (const float*)d_in[4], (const float*)d_in[5],
        (const float*)d_in[6], (const float*)d_in[7], (const float*)d_in[8],
        (const float*)d_in[9], (const float*)d_in[10], ws);
    DoubleLayer_l1_kernel<<<NBROWS/256, 256, 0, stream>>>(x, ws, (unsigned*)d_out);
    DoubleLayer_l2_kernel<<<NBROWS/256, 256, 0, stream>>>(ws, (float*)d_out);
}